// Round 7
// baseline (1338.881 us; speedup 1.0000x reference)
//
#include <hip/hip_runtime.h>

#define DEVINL static __device__ __forceinline__
// Same-wave LDS ordering: compiler reorder fence only (validated r10/r12).
#define CFENCE() asm volatile("" ::: "memory")

typedef float v2f __attribute__((ext_vector_type(2)));

DEVINL v2f mk2(float a, float b) { v2f r; r.x = a; r.y = b; return r; }
DEVINL v2f pkfma(v2f a, v2f b, v2f c) { return __builtin_elementwise_fma(a, b, c); }

constexpr float KE = 2.885390081777927f;   // 2*log2(e)

#if __has_builtin(__builtin_amdgcn_exp2f)
DEVINL float exp2_fast(float x) { return __builtin_amdgcn_exp2f(x); }
#else
DEVINL float exp2_fast(float x) { return __expf(x * 0.6931471805599453f); }
#endif

// tanh(x) with t = x*2*log2(e) pre-folded into weights: 1 - 2/(2^t+1).
DEVINL float tanh_pre(float t) {
  float e = exp2_fast(t);
  return 1.0f - 2.0f * __builtin_amdgcn_rcpf(e + 1.0f);
}

template <int CTRL>
DEVINL float dpp_add(float v) {
  int t = __builtin_amdgcn_update_dpp(0, __float_as_int(v), CTRL, 0xF, 0xF, true);
  return v + __int_as_float(t);
}
DEVINL float rlane(float v, int l) {
  return __int_as_float(__builtin_amdgcn_readlane(__float_as_int(v), l));
}
// 4-stage row-local DPP partial sums; 32-sums via readlane pairs
// (commutative pair-add, bit-identical to row_bcast15 variant; validated).
DEVINL float psum4(float v) {
  v = dpp_add<0xB1>(v);    // quad_perm [1,0,3,2]
  v = dpp_add<0x4E>(v);    // quad_perm [2,3,0,1]
  v = dpp_add<0x141>(v);   // row_half_mirror
  v = dpp_add<0x140>(v);   // row_mirror -> 16-sums per row
  return v;
}

constexpr int TT = 256;

// 256-thread block = 4 waves = 4 elements (one per wave), each wave using
// the validated duty-split layout (lanes 0-31 = r1/z duties, 32-63 = r2/z4).
// ALL weight columns live in LDS (WT), filled once by wave 0: each use is a
// single ds_read_b64 with an immediate offset (no address math, no global
// reload tax — the allocator refuses to keep them in VGPRs; rounds 2/4/6).
// grid 1024 -> 4 blocks/CU = 16 waves/CU = 4 waves/EU, same TLP as R1.
__global__ __attribute__((amdgpu_flat_work_group_size(256, 256))) void reac_kernel(
    const float* __restrict__ useq,   // [B][T] f32
    const float* __restrict__ xz0,    // [B][26] f32
    const float* __restrict__ r1W0, const float* __restrict__ r1b0,
    const float* __restrict__ r1W1, const float* __restrict__ r1b1,
    const float* __restrict__ r1W2, const float* __restrict__ r1b2,
    const float* __restrict__ r2W0, const float* __restrict__ r2b0,
    const float* __restrict__ r2W1, const float* __restrict__ r2b1,
    const float* __restrict__ r2W2, const float* __restrict__ r2b2,
    const float* __restrict__ r3W0, const float* __restrict__ r3b0,
    const float* __restrict__ r3W1, const float* __restrict__ r3b1,
    const float* __restrict__ r3W2, const float* __restrict__ r3b2,
    float2* __restrict__ out)         // [B][T] -> (x0,x1) f32
{
  const int tid = threadIdx.x;
  const int w = tid >> 6;            // wave id 0..3
  const int ln = tid & 63;           // lane within wave
  const int j = ln & 31;
  const bool hi = ln >= 32;          // duty selector (r2 net / z4 duties)
  const int ge = blockIdx.x * 4 + w; // global element index
  const int xaddr = ((ln ^ 32) << 2);

  auto xchg = [&](float v) -> float {
    return __int_as_float(__builtin_amdgcn_ds_bpermute(xaddr, __float_as_int(v)));
  };

  // Weight table: [slot][lane] v2f. Slots: 0-15 W1 (stage layer-1),
  // 16-27 W0C (r3 layer-0, per-half z/z4 mapping), 28-35 W1C (r3 layer-1,
  // per-half k-slice), 36 WX (r3 layer-0 x-pair). 18.9 KB.
  __shared__ __align__(16) v2f WT[37][64];
  // Per-wave private state: [0..23] zs, [32..95] h12 (2x32), [96..191] hR3.
  __shared__ __align__(16) float priv[4][192];
  float* zs  = &priv[w][0];
  float* h12 = &priv[w][32];
  float* hR3 = &priv[w][96];

  // ---- per-half scalars (registers; allocator keeps these fine) ----
  const float* B0p = hi ? r2b0 : r1b0;
  const float* B1p = hi ? r2b1 : r1b1;
  float w0K = (hi ? r2W0 : r1W0)[j] * KE, b0K = B0p[j] * KE;
  float b1K = B1p[j] * KE;
  float w2sc = (hi ? r2W2 : r1W2)[j] * (hi ? 0.2f : 0.3f);
  float b0CK = r3b0[j] * KE, b1CK = r3b1[j] * KE;
  float w2C02 = r3W2[j] * 0.2f;
  const float b2sA = r1b2[0] * 0.3f;
  const float b2sB = r2b2[0] * 0.2f;
  const float b2Cs = r3b2[0] * 0.2f - 0.05f;   // folds -F/V*0.5 of dCb
  const int kbase = hi ? 16 : 0;

  // ---- WT fill (wave 0 covers all 64 (j,hi) combos) ----
  if (tid < 64) {
    const float* W1p = hi ? r2W1 : r1W1;
#pragma unroll
    for (int k = 0; k < 16; ++k)
      WT[k][ln] = mk2(W1p[(2 * k) * 32 + j] * KE,
                      W1p[(2 * k + 1) * 32 + j] * KE);
#pragma unroll
    for (int m = 0; m < 12; ++m) {
      int r = (hi && m >= 1 && m <= 7) ? (2 * m - 2) : (2 * m);
      v2f wv = mk2(r3W0[r * 32 + j] * KE, r3W0[(r + 1) * 32 + j] * KE);
      if (hi && m == 0) wv = mk2(0.f, 0.f);
      WT[16 + m][ln] = wv;
    }
#pragma unroll
    for (int k = 0; k < 8; ++k)
      WT[28 + k][ln] = mk2(r3W1[(kbase + 2 * k) * 32 + j] * KE,
                           r3W1[(kbase + 2 * k + 1) * 32 + j] * KE);
    WT[36][ln] = mk2(r3W0[14 * 32 + j] * KE, r3W0[15 * 32 + j] * KE);
  }

  float x0 = xz0[ge * 26 + 0];
  float x1 = xz0[ge * 26 + 1];
  if (!hi && j < 24) zs[j] = xz0[ge * 26 + 2 + j];
  __syncthreads();                     // WT + zs visible to all waves

  // 32-wide dot vs LDS h-row (uniform addr per half), W from WT slots 0-15.
  auto dot32W = [&](const float* hrow, float bias) -> float {
    const float4* hp = (const float4*)hrow;
    v2f a0 = mk2(bias, 0.f), a1 = mk2(0.f, 0.f);
    v2f a2 = mk2(0.f, 0.f), a3 = mk2(0.f, 0.f);
#pragma unroll
    for (int q = 0; q < 8; q += 2) {
      float4 x = hp[q], y = hp[q + 1];
      a0 = pkfma(mk2(x.x, x.y), WT[2 * q + 0][ln], a0);
      a1 = pkfma(mk2(x.z, x.w), WT[2 * q + 1][ln], a1);
      a2 = pkfma(mk2(y.x, y.y), WT[2 * q + 2][ln], a2);
      a3 = pkfma(mk2(y.z, y.w), WT[2 * q + 3][ln], a3);
    }
    v2f s = (a0 + a1) + (a2 + a3);
    return s.x + s.y;
  };
  // 16-wide partial dot (k-split r3 layer 1), W from WT slots 28-35.
  auto pdot16W = [&](const float* hrow) -> float {
    const float4* hp = (const float4*)hrow;
    v2f a0 = mk2(0.f, 0.f), a1 = mk2(0.f, 0.f);
    float4 x = hp[0], y = hp[1];
    a0 = pkfma(mk2(x.x, x.y), WT[28][ln], a0);
    a1 = pkfma(mk2(x.z, x.w), WT[29][ln], a1);
    a0 = pkfma(mk2(y.x, y.y), WT[30][ln], a0);
    a1 = pkfma(mk2(y.z, y.w), WT[31][ln], a1);
    x = hp[2]; y = hp[3];
    a0 = pkfma(mk2(x.x, x.y), WT[32][ln], a0);
    a1 = pkfma(mk2(x.z, x.w), WT[33][ln], a1);
    a0 = pkfma(mk2(y.x, y.y), WT[34][ln], a0);
    a1 = pkfma(mk2(y.z, y.w), WT[35][ln], a1);
    v2f s = a0 + a1;
    return s.x + s.y;
  };
  // r3 layer-0: low lanes accumulate A(z), high lanes the A(z4)-prefix.
  auto r3_l0 = [&](v2f& aaO, v2f& abO) {
    const float4* zp = (const float4*)zs;
    float4 z0 = zp[0], z1 = zp[1], z2 = zp[2], z3 = zp[3];
    float4 u0 = zp[4], u1 = zp[5];
    v2f aa = mk2(b0CK, 0.f), ab = mk2(0.f, 0.f);
    aa = pkfma(mk2(z0.x, z0.y), WT[16][ln], aa);
    ab = pkfma(mk2(z0.z, z0.w), WT[17][ln], ab);
    aa = pkfma(mk2(z1.x, z1.y), WT[18][ln], aa);
    ab = pkfma(mk2(z1.z, z1.w), WT[19][ln], ab);
    aa = pkfma(mk2(z2.x, z2.y), WT[20][ln], aa);
    ab = pkfma(mk2(z2.z, z2.w), WT[21][ln], ab);
    aa = pkfma(mk2(z3.x, z3.y), WT[22][ln], aa);
    ab = pkfma(mk2(z3.z, z3.w), WT[23][ln], ab);
    aa = pkfma(mk2(u0.x, u0.y), WT[24][ln], aa);
    ab = pkfma(mk2(u0.z, u0.w), WT[25][ln], ab);
    aa = pkfma(mk2(u1.x, u1.y), WT[26][ln], aa);
    ab = pkfma(mk2(u1.z, u1.w), WT[27][ln], ab);
    aaO = aa; abO = ab;
  };
  auto rc1_eval = [&]() -> float {
    float p0 = pdot16W(&hR3[kbase]);
    float o0 = p0 + xchg(p0) + b1CK;
    float v = psum4(tanh_pre(o0) * w2C02);
    return (rlane(v, 15) + rlane(v, 31)) + b2Cs;
  };
  auto net_pre = [&](float sxv, float syv) -> float {
    float sv = hi ? syv : sxv;
    return tanh_pre(fmaf(sv, w0K, b0K));
  };
  auto net_post = [&](float sxv, float syv, float rc_m05, float CafF,
                      float& kx, float& ky) {
    float a = dot32W(&h12[hi ? 32 : 0], b1K);
    float v = psum4(tanh_pre(a) * w2sc);
    float ra = (rlane(v, 15) + rlane(v, 31)) + b2sA;   // r1 (uniform)
    float rb = (rlane(v, 47) + rlane(v, 63)) + b2sB;   // r2 (uniform)
    float dCa = fmaf(-0.03f, sxv, CafF) - ra;
    float dCb = fmaf(-0.02f, syv, fmaf(-3.0f, rb, ra) + rc_m05);
    kx = dCa * (1.0f / 0.3f);
    ky = dCb * (1.0f / 0.2f);
  };

  // ---- prologue: pipeline state for t=0 ----
  v2f aa4, ab4;            // carried A(z4)-prefix accumulators (high half)
  float Az;                // carried A(z_t) (low half)
  r3_l0(aa4, ab4);
  {
    v2f s = aa4 + ab4;
    Az = s.x + s.y;
    float h0 = tanh_pre(Az);
    CFENCE();
    if (!hi) hR3[j] = h0;
    CFENCE();
  }
  float rc1 = rc1_eval();

  const float* up = useq + ge * TT;
  float2* outp = out + ge * TT;
  float u = up[0];

  for (int t = 0; t < TT; ++t) {
    int tn = (t < TT - 1) ? (t + 1) : t;
    float u_nxt = up[tn];              // prefetch, consumed next iter
    float CafF = fmaf(u, 0.05f, 0.05f);

    if (ln == 0) outp[t] = make_float2(x0, x1);

    // R0: z4 completion + z23 by linearity; stage-1 hiddens.
    ab4 = pkfma(mk2(x0, x1), WT[36][ln], ab4);
    v2f s4v = aa4 + ab4;
    float A4 = s4v.x + s4v.y;               // A(z4), high lanes
    float Apart = xchg(hi ? A4 : Az);
    float targ = hi ? A4 : (0.5f * (Az + Apart));   // z23 on low half
    float hh = tanh_pre(targ);
    float h1 = net_pre(x0, x1);
    CFENCE();
    // R1: LDS broadcasts
    hR3[32 * (1 + (hi ? 1 : 0)) + j] = hh;  // low->h(z23), high->h(z4)
    h12[(hi ? 32 : 0) + j] = h1;
    CFENCE();
    // R2: head finish (rc23, rc4) || stage-1 finish || stage-2 layer-0
    float p1 = pdot16W(&hR3[32 + kbase]);
    float p2 = pdot16W(&hR3[64 + kbase]);
    float o1 = p1 + xchg(p1) + b1CK;
    float o2 = p2 + xchg(p2) + b1CK;
    float vv = psum4(tanh_pre(hi ? o2 : o1) * w2C02);
    float rc23 = (rlane(vv, 15) + rlane(vv, 31)) + b2Cs;
    float rc4  = (rlane(vv, 47) + rlane(vv, 63)) + b2Cs;
    float kx1, ky1;
    net_post(x0, x1, rc1, CafF, kx1, ky1);
    float sx2 = fmaf(kx1, 0.5f, x0), sy2 = fmaf(ky1, 0.5f, x1);
    float h2 = net_pre(sx2, sy2);
    CFENCE();
    // R3
    h12[(hi ? 32 : 0) + j] = h2;
    CFENCE();
    // R4a: stage-2 finish || z-shift (reads then fenced write)
    float kx2, ky2;
    net_post(sx2, sy2, rc23, CafF, kx2, ky2);
    {
      // zplus = [zs[2:16], x0, x1, zs[17:24], u]
      int src = (j < 14) ? (j + 2) : ((j < 23) ? (j + 1) : 0);
      float zread = zs[src];
      float znew = (j == 14) ? x0 : ((j == 15) ? x1 : ((j == 23) ? u : zread));
      if ((!hi) && (j < 24)) zs[j] = znew;
    }
    CFENCE();
    // R4b: r3 layer-0 for t+1 (reads shifted zs) || stage-3 layer-0
    r3_l0(aa4, ab4);
    {
      v2f sv2 = aa4 + ab4;
      Az = sv2.x + sv2.y;                  // A(z_{t+1}) on low lanes
      float h0n = tanh_pre(Az);
      if (!hi) hR3[j] = h0n;               // h(z_{t+1})
    }
    float sx3 = fmaf(kx2, 0.5f, x0), sy3 = fmaf(ky2, 0.5f, x1);
    float h3 = net_pre(sx3, sy3);
    CFENCE();
    // R5
    h12[(hi ? 32 : 0) + j] = h3;
    CFENCE();
    // R6: stage-3 finish || rc1 for t+1 || stage-4 layer-0
    float kx3, ky3;
    net_post(sx3, sy3, rc23, CafF, kx3, ky3);
    rc1 = rc1_eval();
    float sx4 = x0 + kx3, sy4 = x1 + ky3;
    float h4 = net_pre(sx4, sy4);
    CFENCE();
    // R7
    h12[(hi ? 32 : 0) + j] = h4;
    CFENCE();
    // R8: stage-4 finish, state update
    float kx4, ky4;
    net_post(sx4, sy4, rc4, CafF, kx4, ky4);
    x0 += (kx1 + 2.0f * (kx2 + kx3) + kx4) * (1.0f / 6.0f);
    x1 += (ky1 + 2.0f * (ky2 + ky3) + ky4) * (1.0f / 6.0f);
    u = u_nxt;
    CFENCE();
  }
}

extern "C" void kernel_launch(void* const* d_in, const int* in_sizes, int n_in,
                              void* d_out, int out_size, void* d_ws, size_t ws_size,
                              hipStream_t stream) {
  const float* p[20];
  for (int i = 0; i < 20; ++i) p[i] = (const float*)d_in[i];
  reac_kernel<<<dim3(1024), dim3(256), 0, stream>>>(
      p[0], p[1], p[2], p[3], p[4], p[5], p[6], p[7], p[8], p[9], p[10],
      p[11], p[12], p[13], p[14], p[15], p[16], p[17], p[18], p[19],
      (float2*)d_out);
}